// Round 7
// baseline (155.209 us; speedup 1.0000x reference)
//
#include <hip/hip_runtime.h>
#include <hip/hip_bf16.h>
#include <math.h>

#define NBATCH 16
#define NA     128
#define CH     512
#define EFEAT  30

typedef __attribute__((ext_vector_type(8))) short          bf16x8;
typedef __attribute__((ext_vector_type(4))) float          f32x4;
typedef __attribute__((ext_vector_type(8))) unsigned short ushort8;
typedef __attribute__((ext_vector_type(4))) unsigned short ushort4_t;

__device__ __forceinline__ float selu_f(float x) {
    const float SA = 1.7580993408473766f;     // scale*alpha
    float e = __expf(x);
    return x > 0.0f ? 1.0507009873554805f * x : fmaf(SA, e, -SA);
}

__device__ __forceinline__ unsigned short f2bf(float f) {
    __hip_bfloat16 h = __float2bfloat16(f);   // RNE
    return *reinterpret_cast<unsigned short*>(&h);
}

// -------------------------------------------------------------------------
// Kernel 0: one-shot f32 -> bf16 convert of wW into workspace (after z).
// 512x1024 = 131072 float4, grid 512 x 256 threads = exactly 1 float4 each.
// -------------------------------------------------------------------------
__global__ __launch_bounds__(256)
void k_cvt_w(const float* __restrict__ wW, unsigned short* __restrict__ wWb)
{
    const int i = (blockIdx.x * 256 + threadIdx.x) * 4;
    const f32x4 v = *(const f32x4*)&wW[i];
    ushort4_t o;
    o.x = f2bf(v[0]); o.y = f2bf(v[1]); o.z = f2bf(v[2]); o.w = f2bf(v[3]);
    *(ushort4_t*)&wWb[i] = o;
}

// -------------------------------------------------------------------------
// Kernel 1: edge filter + SELU + mask + aggregation (MFMA, live-j compacted).
//   S[c,p] = fW[c,:30]·e[row,jlist[p],:30] + fb[c]  (bias in k=30 pad slot)
//   h1[c] = sum_{p<nlive} selu(S[c,p]) * h[b,jlist[p],c]
// R7 change: e row staged COALESCED (float4, uncompacted -> [128][40] bf16
// LDS), no jlist-dependent global gather; compaction applied at READ time
// (bfrag row = jlist[p]). Staging issues before the ballot barriers resolve.
// D layout: col=lane&15=p, row=(lane>>4)*4+q=c -> h is one float4/lane;
// j-reduce = shfl_xor{1,2,4,8}.
// -------------------------------------------------------------------------
__global__ __launch_bounds__(256, 4)
void k_edge_mfma(const float* __restrict__ h, const float* __restrict__ e,
                 const float* __restrict__ node_mask, const float* __restrict__ edge_mask,
                 const float* __restrict__ fW, const float* __restrict__ fb,
                 unsigned short* __restrict__ z)
{
    __shared__ unsigned short e_lds[NA * 40];   // [128][40] bf16; k30=1.0 (bias), k31=0
    __shared__ int   jlist[NA];
    __shared__ int   wcnt[2];

    const int row = (blockIdx.x & 7) * 256 + (blockIdx.x >> 3);  // XCD swizzle
    if (node_mask[row] == 0.0f) return;          // block-uniform early exit
    const int b = row >> 7;

    const int tid  = threadIdx.x;
    const int lane = tid & 63;
    const int wv   = tid >> 6;
    const int s    = lane & 15;                  // fragment col (compact p)
    const int g    = lane >> 4;                  // k-group / row-group
    const int cbase = wv * 128;                  // wave owns 128 channels

    // ballot of live j (edge_mask is exactly 0 or 1)
    float myq = 0.0f; unsigned long long bl = 0;
    if (tid < NA) {
        myq = edge_mask[(size_t)row * NA + tid];
        bl = __ballot(myq != 0.0f);
        if ((tid & 63) == 0) wcnt[tid >> 6] = __popcll(bl);
    }

    // stage FULL e row coalesced: 3840 f32 = 960 float4 (no jlist dependency)
    const f32x4* esrc4 = (const f32x4*)(e + (size_t)row * (NA * EFEAT));
    #pragma unroll
    for (int it = 0; it < 4; ++it) {
        const int v4 = tid + it * 256;
        if (v4 < 960) {
            const f32x4 x = esrc4[v4];
            const int flat = v4 * 4;
            #pragma unroll
            for (int u = 0; u < 4; ++u) {
                const int fl = flat + u;
                const int j  = fl / 30;          // const-div -> magic mul
                const int f  = fl - j * 30;
                e_lds[j * 40 + f] = f2bf(x[u]);
            }
        }
    }
    if (tid < NA) {                              // bias slot + pad
        e_lds[tid * 40 + 30] = f2bf(1.0f);
        e_lds[tid * 40 + 31] = 0;
    }

    // A-fragments: fW rows + fb in k=30 slot.  lane: c=cbase+cf*16+s, k=g*8+e8
    bf16x8 afrag[8];
    #pragma unroll
    for (int cf = 0; cf < 8; ++cf) {
        const int c = cbase + cf * 16 + s;
        const float* wrow = fW + (size_t)c * EFEAT;
        ushort8 t;
        #pragma unroll
        for (int e8 = 0; e8 < 8; ++e8) {
            const int k = g * 8 + e8;
            const float v = (k < EFEAT) ? wrow[k] : (k == EFEAT ? fb[c] : 0.0f);
            t[e8] = f2bf(v);
        }
        afrag[cf] = *(bf16x8*)&t;
    }

    // z-row echo of h (independent; issue early)
    unsigned short* zrow = z + (size_t)row * (2 * CH);
    const float* hrow = h + (size_t)row * CH;
    zrow[tid]       = f2bf(hrow[tid]);
    zrow[tid + 256] = f2bf(hrow[tid + 256]);

    __syncthreads();                             // wcnt + e_lds ready
    const int nlive  = wcnt[0] + wcnt[1];
    const int ntiles = (nlive + 15) >> 4;
    if (tid < NA) {
        if (myq != 0.0f) {
            const int base = (tid >= 64) ? wcnt[0] : 0;
            const int pos  = __popcll(bl & ((1ull << (tid & 63)) - 1));
            jlist[base + pos] = tid;
        }
        if (tid >= nlive) jlist[tid] = 0;        // pads (disjoint slots)
    }
    __syncthreads();                             // jlist ready

    f32x4 acc[8];
    #pragma unroll
    for (int cf = 0; cf < 8; ++cf) acc[cf] = (f32x4){0.f, 0.f, 0.f, 0.f};

    #pragma unroll 2
    for (int jt = 0; jt < ntiles; ++jt) {
        const int   p   = jt * 16 + s;
        const float emj = (p < nlive) ? 1.0f : 0.0f;     // pad gate
        const int   jj  = jlist[p];                      // LDS read (16 ints)
        const bf16x8 bfrag = *(const bf16x8*)&e_lds[jj * 40 + g * 8];
        const float* hbase = h + ((size_t)(b * NA) + jj) * CH;
        f32x4 hv[8];
        #pragma unroll
        for (int cf = 0; cf < 8; ++cf)           // 8 independent loads in flight
            hv[cf] = *(const f32x4*)&hbase[cbase + cf * 16 + g * 4];
        #pragma unroll
        for (int cf = 0; cf < 8; ++cf) {
            f32x4 S = __builtin_amdgcn_mfma_f32_16x16x32_bf16(
                          afrag[cf], bfrag, (f32x4){0.f, 0.f, 0.f, 0.f}, 0, 0, 0);
            #pragma unroll
            for (int q = 0; q < 4; ++q) {
                const float sv = selu_f(S[q]);           // bias already in S
                acc[cf][q] = fmaf(emj, sv * hv[cf][q], acc[cf][q]);
            }
        }
    }

    // reduce over compact p across the 16 s-lanes of each g-group
    #pragma unroll
    for (int m = 1; m <= 8; m <<= 1)
        #pragma unroll
        for (int cf = 0; cf < 8; ++cf)
            #pragma unroll
            for (int q = 0; q < 4; ++q)
                acc[cf][q] += __shfl_xor(acc[cf][q], m, 64);

    if (s == 0) {                                // lanes 0,16,32,48 hold sums
        #pragma unroll
        for (int cf = 0; cf < 8; ++cf) {
            const int c0 = cbase + cf * 16 + g * 4;
            ushort4_t o;
            #pragma unroll
            for (int q = 0; q < 4; ++q) o[q] = f2bf(acc[cf][q]);
            *(ushort4_t*)&zrow[CH + c0] = o;
        }
    }
}

// -------------------------------------------------------------------------
// Kernel 2: node MLP GEMM — barrier-free, LDS-free, all-bf16 operands.
// C = z(2048x1024 bf16) @ wWb^T(512x1024 bf16); out = selu(C+wb)*nm + h.
// 32x32 tiles -> grid 1024 (4 blocks/CU, 16 waves/CU). Each wave = one
// 16x16 quadrant; A/B fragments loaded straight global->VGPR (L2-resident,
// z=4MB + wWb=1MB per XCD panel), K-loop unroll 4 -> 8 loads in flight,
// ZERO __syncthreads. Dead z rows are 0xAA poison (finite bf16); nm=0
// masks them in the epilogue. XCD swizzle shares the wWb panel.
// -------------------------------------------------------------------------
__global__ __launch_bounds__(256, 4)
void k_node_mlp(const float* __restrict__ h, const unsigned short* __restrict__ z,
                const float* __restrict__ node_mask,
                const unsigned short* __restrict__ wWb, const float* __restrict__ wb,
                float* __restrict__ out)
{
    const int tid  = threadIdx.x;
    const int bid  = (blockIdx.x & 7) * 128 + (blockIdx.x >> 3);  // 1024 = 8*128
    const int m0   = (bid >> 4) * 32;
    const int n0   = (bid & 15) * 32;
    const int lane = tid & 63, wv = tid >> 6;
    const int wr = wv >> 1, wc = wv & 1;
    const int s  = lane & 15, g = lane >> 4;

    const unsigned short* A0 = z   + (size_t)(m0 + wr * 16 + s) * (2 * CH) + g * 8;
    const unsigned short* B0 = wWb + (size_t)(n0 + wc * 16 + s) * (2 * CH) + g * 8;

    f32x4 acc = {0.f, 0.f, 0.f, 0.f};

    #pragma unroll 4
    for (int ks = 0; ks < 2 * CH; ks += 32) {
        const bf16x8 a = *(const bf16x8*)&A0[ks];
        const bf16x8 bfr = *(const bf16x8*)&B0[ks];
        acc = __builtin_amdgcn_mfma_f32_16x16x32_bf16(a, bfr, acc, 0, 0, 0);
    }

    // epilogue: D col=s (n), row=g*4+q (m)
    const int r0 = m0 + wr * 16 + g * 4;
    const int c  = n0 + wc * 16 + s;
    const float wbv = wb[c];
    const f32x4 nmv = *(const f32x4*)&node_mask[r0];
    #pragma unroll
    for (int q = 0; q < 4; ++q) {
        const size_t gi = (size_t)(r0 + q) * CH + c;
        out[gi] = selu_f(acc[q] + wbv) * nmv[q] + h[gi];
    }
}

extern "C" void kernel_launch(void* const* d_in, const int* in_sizes, int n_in,
                              void* d_out, int out_size, void* d_ws, size_t ws_size,
                              hipStream_t stream)
{
    (void)in_sizes; (void)n_in; (void)out_size; (void)ws_size;
    const float* h  = (const float*)d_in[0];
    const float* e  = (const float*)d_in[1];
    const float* nm = (const float*)d_in[2];
    const float* em = (const float*)d_in[3];
    const float* fW = (const float*)d_in[4];
    const float* fb = (const float*)d_in[5];
    const float* wW = (const float*)d_in[6];
    const float* wb = (const float*)d_in[7];
    float* out = (float*)d_out;
    unsigned short* z   = (unsigned short*)d_ws;            // 2048x1024 bf16 = 4 MB
    unsigned short* wWb = (unsigned short*)d_ws + 2048*1024; // 512x1024 bf16 = 1 MB

    k_cvt_w<<<512, 256, 0, stream>>>(wW, wWb);
    k_edge_mfma<<<NBATCH * NA, 256, 0, stream>>>(h, e, nm, em, fW, fb, z);
    k_node_mlp<<<(NBATCH * NA / 32) * (CH / 32), 256, 0, stream>>>(h, z, nm, wWb, wb, out);
}